// Round 3
// baseline (15197.702 us; speedup 1.0000x reference)
//
#include <hip/hip_runtime.h>
#include <math.h>

// Problem constants (fixed by reference file)
#define NB   512    // N = batch of user pairs
#define MM   254    // M uav nodes
#define SS   256    // S = M + 2 graph nodes per b
#define HH   128    // H hidden
#define RTOT 1278   // 2N + M rows in `outputs`

__device__ __forceinline__ float sigm(float x)   { return 1.0f / (1.0f + __expf(-x)); }
__device__ __forceinline__ float tanh_f(float x) { return 1.0f - 2.0f / (1.0f + __expf(2.0f * x)); }

// Per node row r: e = pos @ W_embed + b_embed (128),
//   W1eT[h][r] = (e @ att_W1)[h]            (transposed: lane-coalesced over r)
//   EWi[r][j]  = (e @ lstm_Wi)[j] + lstm_b  (bias folded; lane-coalesced over j)
__global__ __launch_bounds__(128) void precompute_k(
    const float* __restrict__ outputs, const float* __restrict__ Wemb,
    const float* __restrict__ bemb, const float* __restrict__ Wi,
    const float* __restrict__ W1, const float* __restrict__ lb,
    float* __restrict__ EWi, float* __restrict__ W1eT)
{
  int r = blockIdx.x;
  int t = threadIdx.x;  // 128
  __shared__ float e[HH];
  float px = outputs[2 * r], py = outputs[2 * r + 1];
  e[t] = px * Wemb[t] + py * Wemb[HH + t] + bemb[t];
  __syncthreads();
  float acc = 0.f;
#pragma unroll 8
  for (int h = 0; h < HH; ++h) acc = fmaf(e[h], W1[h * HH + t], acc);
  W1eT[(size_t)t * RTOT + r] = acc;
#pragma unroll
  for (int c4 = 0; c4 < 4; ++c4) {
    int j = t + c4 * HH;
    float a = 0.f;
#pragma unroll 8
    for (int h = 0; h < HH; ++h) a = fmaf(e[h], Wi[h * 512 + j], a);
    EWi[(size_t)r * 512 + j] = a + lb[j];
  }
}

// One block per batch element b. 512 threads (8 waves), 2 blocks/CU.
__global__ __launch_bounds__(512, 4) void decode_k(
    const float* __restrict__ outputs, const float* __restrict__ Wh,
    const float* __restrict__ W2, const float* __restrict__ av,
    const float* __restrict__ EWi, const float* __restrict__ W1eT,
    float* __restrict__ maxd_out)
{
  int b = blockIdx.x;
  int t = threadIdx.x;  // 512

  __shared__ float posS[2 * RTOT];          // all node positions (10.2 KB)
  __shared__ float hS[HH], cS[HH], qS[HH], vS[HH];
  __shared__ float gS[512];
  __shared__ float qpS[4][HH];
  __shared__ float wvalS[8];
  __shared__ unsigned wkeyS[8];
  __shared__ int actS[254];
  __shared__ int cntS, curS;

  for (int i = t; i < 2 * RTOT; i += 512) posS[i] = outputs[i];
  if (t < HH) { hS[t] = 0.f; cS[t] = 0.f; vS[t] = av[t]; }
  if (t < 254) actS[t] = t + 1;             // s = 1..254 initially active
  if (t == 0) { cntS = 254; curS = b; }
  __syncthreads();

  float px = 0.f, py = 0.f, md = 0.f;       // live only in thread 0
  if (t == 0) { px = posS[2 * b]; py = posS[2 * b + 1]; }

  const int jq  = t & (HH - 1);             // q-GEMV split
  const int seg = t >> 7;                   // 0..3

  for (int k = 0; k < SS; ++k) {
    int cur = curS;
    int cnt = cntS;

    // ---- gates[j=t] = EWi[cur][t] + sum_kk h[kk]*Wh[kk][t]
    // Original Wh layout: lane-consecutive t -> coalesced. Full unroll,
    // 4 accumulators for deep load pipelining.
    {
      float a0 = EWi[(size_t)cur * 512 + t];
      float a1 = 0.f, a2 = 0.f, a3 = 0.f;
      const float* wp = Wh + t;
#pragma unroll
      for (int kk = 0; kk < HH; kk += 4) {
        a0 = fmaf(hS[kk + 0], wp[(size_t)(kk + 0) * 512], a0);
        a1 = fmaf(hS[kk + 1], wp[(size_t)(kk + 1) * 512], a1);
        a2 = fmaf(hS[kk + 2], wp[(size_t)(kk + 2) * 512], a2);
        a3 = fmaf(hS[kk + 3], wp[(size_t)(kk + 3) * 512], a3);
      }
      gS[t] = (a0 + a1) + (a2 + a3);
    }
    __syncthreads();

    // ---- LSTM cell (order: i, f, g, o)
    if (t < HH) {
      float iv = sigm(gS[t]);
      float fv = sigm(gS[HH + t]);
      float gv = tanh_f(gS[2 * HH + t]);
      float ov = sigm(gS[3 * HH + t]);
      float cn = fv * cS[t] + iv * gv;
      cS[t] = cn;
      hS[t] = ov * tanh_f(cn);
    }
    __syncthreads();

    // ---- q[j] = sum_kk h[kk]*W2[kk][j], 4-way split-K across 512 threads
    {
      float p0 = 0.f, p1 = 0.f;
      const float* wp = W2 + (size_t)(seg * 32) * HH + jq;
#pragma unroll
      for (int kk = 0; kk < 32; kk += 2) {
        p0 = fmaf(hS[seg * 32 + kk + 0], wp[(size_t)(kk + 0) * HH], p0);
        p1 = fmaf(hS[seg * 32 + kk + 1], wp[(size_t)(kk + 1) * HH], p1);
      }
      qpS[seg][jq] = p0 + p1;
    }
    __syncthreads();
    if (t < HH) qS[t] = (qpS[0][t] + qpS[1][t]) + (qpS[2][t] + qpS[3][t]);
    __syncthreads();

    // ---- logits over active nodes; W1eT[h][r]: lane-coalesced over r
    int cntEff = cnt + (k > 0 ? 1 : 0);     // node 255 re-enters for k>0
    float val = -INFINITY;
    unsigned key = 0xFFFFFFFFu;
    if (t < cntEff) {
      int s = (t == cnt) ? 255 : actS[t];
      int r = (s == 255) ? (NB + b) : (2 * NB + (s - 1));
      const float* wp = W1eT + r;
      float c0 = 0.f, c1 = 0.f, c2 = 0.f, c3 = 0.f;
#pragma unroll
      for (int h = 0; h < HH; h += 4) {
        c0 = fmaf(vS[h + 0], tanh_f(wp[(size_t)(h + 0) * RTOT] + qS[h + 0]), c0);
        c1 = fmaf(vS[h + 1], tanh_f(wp[(size_t)(h + 1) * RTOT] + qS[h + 1]), c1);
        c2 = fmaf(vS[h + 2], tanh_f(wp[(size_t)(h + 2) * RTOT] + qS[h + 2]), c2);
        c3 = fmaf(vS[h + 3], tanh_f(wp[(size_t)(h + 3) * RTOT] + qS[h + 3]), c3);
      }
      val = (c0 + c1) + (c2 + c3);
      key = ((unsigned)s << 16) | (unsigned)t;  // tie-break: smaller s wins
    }
    // wave-level argmax (no barrier)
#pragma unroll
    for (int off = 1; off < 64; off <<= 1) {
      float v2 = __shfl_xor(val, off);
      unsigned k2 = __shfl_xor(key, off);
      if (v2 > val || (v2 == val && k2 < key)) { val = v2; key = k2; }
    }
    if ((t & 63) == 0) { wvalS[t >> 6] = val; wkeyS[t >> 6] = key; }
    __syncthreads();

    // ---- final pick + state update (thread 0)
    if (t == 0) {
      float bv = wvalS[0]; unsigned bk = wkeyS[0];
#pragma unroll
      for (int w = 1; w < 8; ++w) {
        float v2 = wvalS[w]; unsigned k2 = wkeyS[w];
        if (v2 > bv || (v2 == bv && k2 < bk)) { bv = v2; bk = k2; }
      }
      int s   = (int)(bk >> 16);
      int pos = (int)(bk & 0xFFFFu);
      int rn  = (s == 255) ? (NB + b) : (2 * NB + (s - 1));
      float nx = posS[2 * rn], ny = posS[2 * rn + 1];
      float dx = nx - px, dy = ny - py;
      float d = sqrtf(dx * dx + dy * dy + 1e-12f);
      if (d > md) md = d;
      px = nx; py = ny;
      curS = rn;
      if (s != 255) { actS[pos] = actS[cnt - 1]; cntS = cnt - 1; }
    }
    __syncthreads();
  }
  if (t == 0) maxd_out[b] = md;
}

__global__ __launch_bounds__(512) void reduce_k(const float* __restrict__ maxd,
                                               float* __restrict__ out)
{
  __shared__ float s[512];
  int t = threadIdx.x;
  s[t] = maxd[t];
  __syncthreads();
  for (int off = 256; off > 0; off >>= 1) {
    if (t < off) s[t] += s[t + off];
    __syncthreads();
  }
  if (t == 0) out[0] = s[0] * (1.0f / 512.0f);
}

extern "C" void kernel_launch(void* const* d_in, const int* in_sizes, int n_in,
                              void* d_out, int out_size, void* d_ws, size_t ws_size,
                              hipStream_t stream) {
  const float* outputs = (const float*)d_in[0];
  const float* Wemb    = (const float*)d_in[1];
  const float* bemb    = (const float*)d_in[2];
  const float* Wi      = (const float*)d_in[3];
  const float* Wh      = (const float*)d_in[4];
  const float* lb      = (const float*)d_in[5];
  const float* W1      = (const float*)d_in[6];
  const float* W2      = (const float*)d_in[7];
  const float* av      = (const float*)d_in[8];
  // d_in[9] = N (known constant 512)

  float* ws   = (float*)d_ws;
  float* EWi  = ws;                           // 1278 * 512
  float* W1eT = EWi  + (size_t)RTOT * 512;    // 128 * 1278
  float* maxd = W1eT + (size_t)HH * RTOT;     // 512

  hipLaunchKernelGGL(precompute_k, dim3(RTOT), dim3(HH), 0, stream,
                     outputs, Wemb, bemb, Wi, W1, lb, EWi, W1eT);
  hipLaunchKernelGGL(decode_k, dim3(NB), dim3(512), 0, stream,
                     outputs, Wh, W2, av, EWi, W1eT, maxd);
  hipLaunchKernelGGL(reduce_k, dim3(1), dim3(512), 0, stream, maxd, (float*)d_out);
}

// Round 4
// 3694.115 us; speedup vs baseline: 4.1140x; 4.1140x over previous
//
#include <hip/hip_runtime.h>
#include <math.h>

// Problem constants (fixed by reference file)
#define NB   512    // N = batch of user pairs
#define MM   254    // M uav nodes
#define SS   256    // S = M + 2 graph nodes per b
#define HH   128    // H hidden
#define RTOT 1278   // 2N + M rows in `outputs`
#define NBLK 256    // decode blocks; each handles b and b+256

__device__ __forceinline__ float sigm(float x)   { return 1.0f / (1.0f + __expf(-x)); }
__device__ __forceinline__ float tanh_f(float x) { return 1.0f - 2.0f / (1.0f + __expf(2.0f * x)); }

// Per node row r: e = pos @ W_embed + b_embed (128),
//   W1eT[h][r] = (e @ att_W1)[h]            (transposed: lane-coalesced over r)
//   EWi[r][j]  = (e @ lstm_Wi)[j] + lstm_b  (bias folded; lane-coalesced over j)
__global__ __launch_bounds__(128) void precompute_k(
    const float* __restrict__ outputs, const float* __restrict__ Wemb,
    const float* __restrict__ bemb, const float* __restrict__ Wi,
    const float* __restrict__ W1, const float* __restrict__ lb,
    float* __restrict__ EWi, float* __restrict__ W1eT)
{
  int r = blockIdx.x;
  int t = threadIdx.x;  // 128
  __shared__ float e[HH];
  float px = outputs[2 * r], py = outputs[2 * r + 1];
  e[t] = px * Wemb[t] + py * Wemb[HH + t] + bemb[t];
  __syncthreads();
  float acc = 0.f;
#pragma unroll 8
  for (int h = 0; h < HH; ++h) acc = fmaf(e[h], W1[h * HH + t], acc);
  W1eT[(size_t)t * RTOT + r] = acc;
#pragma unroll
  for (int c4 = 0; c4 < 4; ++c4) {
    int j = t + c4 * HH;
    float a = 0.f;
#pragma unroll 8
    for (int h = 0; h < HH; ++h) a = fmaf(e[h], Wi[h * 512 + j], a);
    EWi[(size_t)r * 512 + j] = a + lb[j];
  }
}

// One block per TWO batch elements (b, b+256). 1024 threads = 16 waves.
// 256 blocks -> 1 block/CU, 16 waves/CU (~50% occupancy).
__global__ __launch_bounds__(1024) void decode_k(
    const float* __restrict__ outputs, const float* __restrict__ Wh,
    const float* __restrict__ W2, const float* __restrict__ av,
    const float* __restrict__ EWi, const float* __restrict__ W1eT,
    float* __restrict__ maxd_out)
{
  const int t = threadIdx.x;  // 0..1023

  __shared__ float posS[2 * RTOT];       // all node positions (10.2 KB)
  __shared__ float hS[2][HH], cS[2][HH], qS[2][HH], vS[HH];
  __shared__ float pS[2][2][512];        // gates split-K partials [g][khalf][j]
  __shared__ float qp[2][4][HH];         // q split-K partials [g][kquarter][j]
  __shared__ float lp[2][2][SS];         // logit partials [g][hhalf][u]
  __shared__ int   lsS[2][SS];           // node id s per slot u
  __shared__ int   actS[2][254];
  __shared__ int   cntS[2], curS[2];

  // init
  for (int i = t; i < 2 * RTOT; i += 1024) posS[i] = outputs[i];
  if (t < 256) { int g = t >> 7, j = t & 127; hS[g][j] = 0.f; cS[g][j] = 0.f; }
  if (t < HH) vS[t] = av[t];
  if (t < 254) actS[0][t] = t + 1;
  else if (t >= 512 && t < 766) actS[1][t - 512] = t - 511;
  if (t == 0)   { cntS[0] = 254; curS[0] = blockIdx.x; }
  if (t == 256) { cntS[1] = 254; curS[1] = blockIdx.x + NBLK; }
  __syncthreads();

  float px = 0.f, py = 0.f, md = 0.f;    // live in t==0 (b0) and t==256 (b1)
  if (t == 0)   { px = posS[2 * blockIdx.x];          py = posS[2 * blockIdx.x + 1]; }
  if (t == 256) { px = posS[2 * (blockIdx.x + NBLK)]; py = posS[2 * (blockIdx.x + NBLK) + 1]; }

  const int gj = t & 511;        // gates output j
  const int gh = t >> 9;         // gates k-half (0/1)
  const int qj = t & 127;        // q output j
  const int qg = (t >> 7) & 1;   // q batch slot
  const int qq = t >> 8;         // q k-quarter (0..3)
  const int lg = t >> 9;         // logits batch slot
  const int lhf = (t >> 8) & 1;  // logits h-half
  const int lu = t & 255;        // logits node slot

  for (int k = 0; k < SS; ++k) {
    // ---- gates split-K partials: pS[g][gh][gj] = sum_{kk in half} h_g[kk]*Wh[kk][gj]
    {
      const float* wp = Wh + (size_t)(gh * 64) * 512 + gj;
      const float* h0 = &hS[0][gh * 64];
      const float* h1 = &hS[1][gh * 64];
      float a00 = 0.f, a01 = 0.f, a10 = 0.f, a11 = 0.f;
#pragma unroll 4
      for (int kk = 0; kk < 64; kk += 2) {
        float w0 = wp[(size_t)kk * 512];
        float w1 = wp[(size_t)(kk + 1) * 512];
        a00 = fmaf(h0[kk],     w0, a00);
        a01 = fmaf(h0[kk + 1], w1, a01);
        a10 = fmaf(h1[kk],     w0, a10);
        a11 = fmaf(h1[kk + 1], w1, a11);
      }
      pS[0][gh][gj] = a00 + a01;
      pS[1][gh][gj] = a10 + a11;
    }
    __syncthreads();  // B1

    // ---- LSTM cell: t<256 covers 2 b x 128 j
    if (t < 256) {
      int g = t >> 7, jj = t & 127;
      const float* ew = EWi + (size_t)curS[g] * 512;
      float ei = ew[jj]        + (pS[g][0][jj]        + pS[g][1][jj]);
      float ef = ew[128 + jj]  + (pS[g][0][128 + jj]  + pS[g][1][128 + jj]);
      float eg = ew[256 + jj]  + (pS[g][0][256 + jj]  + pS[g][1][256 + jj]);
      float eo = ew[384 + jj]  + (pS[g][0][384 + jj]  + pS[g][1][384 + jj]);
      float iv = sigm(ei), fv = sigm(ef), gv = tanh_f(eg), ov = sigm(eo);
      float cn = fv * cS[g][jj] + iv * gv;
      cS[g][jj] = cn;
      hS[g][jj] = ov * tanh_f(cn);
    }
    __syncthreads();  // B2

    // ---- q split-K partials: qp[g][qq][qj] = sum_{kk in quarter} h_g[kk]*W2[kk][qj]
    {
      const float* wp = W2 + (size_t)(qq * 32) * HH + qj;
      const float* hp = &hS[qg][qq * 32];
      float p0 = 0.f, p1 = 0.f;
#pragma unroll 4
      for (int kk = 0; kk < 32; kk += 2) {
        p0 = fmaf(hp[kk],     wp[(size_t)kk * HH],       p0);
        p1 = fmaf(hp[kk + 1], wp[(size_t)(kk + 1) * HH], p1);
      }
      qp[qg][qq][qj] = p0 + p1;
    }
    __syncthreads();  // B3

    if (t < 256) {
      int g = t >> 7, j = t & 127;
      qS[g][j] = (qp[g][0][j] + qp[g][1][j]) + (qp[g][2][j] + qp[g][3][j]);
    }
    __syncthreads();  // B4

    // ---- logit partials over active nodes; W1eT[h][r] lane-coalesced over r
    {
      int cnt = cntS[lg];
      int cntEff = cnt + (k > 0 ? 1 : 0);   // dst node re-enters for k>0
      if (lu < cntEff) {
        int s = (lu == cnt) ? 255 : actS[lg][lu];
        int r = (s == 255) ? (NB + blockIdx.x + (lg << 8)) : (2 * NB + s - 1);
        const float* wp = W1eT + (size_t)(lhf * 64) * RTOT + r;
        const float* qh = &qS[lg][lhf * 64];
        const float* vh = &vS[lhf * 64];
        float c0 = 0.f, c1 = 0.f, c2 = 0.f, c3 = 0.f;
#pragma unroll 2
        for (int h = 0; h < 64; h += 4) {
          c0 = fmaf(vh[h],     tanh_f(wp[(size_t)h * RTOT]       + qh[h]),     c0);
          c1 = fmaf(vh[h + 1], tanh_f(wp[(size_t)(h + 1) * RTOT] + qh[h + 1]), c1);
          c2 = fmaf(vh[h + 2], tanh_f(wp[(size_t)(h + 2) * RTOT] + qh[h + 2]), c2);
          c3 = fmaf(vh[h + 3], tanh_f(wp[(size_t)(h + 3) * RTOT] + qh[h + 3]), c3);
        }
        lp[lg][lhf][lu] = (c0 + c1) + (c2 + c3);
        if (lhf == 0) lsS[lg][lu] = s;
      }
    }
    __syncthreads();  // B5

    // ---- argmax + state update: wave 0 handles b0, wave 4 handles b1
    if ((t < 64) || (t >= 256 && t < 320)) {
      int g = t >> 8;
      int lane = t & 63;
      int cnt = cntS[g];
      int cntEff = cnt + (k > 0 ? 1 : 0);
      float val = -INFINITY;
      unsigned key = 0xFFFFFFFFu;
#pragma unroll
      for (int c4 = 0; c4 < 4; ++c4) {
        int u = lane + 64 * c4;
        if (u < cntEff) {
          float v2 = lp[g][0][u] + lp[g][1][u];
          unsigned k2 = ((unsigned)lsS[g][u] << 16) | (unsigned)u;
          if (v2 > val || (v2 == val && k2 < key)) { val = v2; key = k2; }
        }
      }
#pragma unroll
      for (int off = 1; off < 64; off <<= 1) {
        float v2 = __shfl_xor(val, off);
        unsigned k2 = __shfl_xor(key, off);
        if (v2 > val || (v2 == val && k2 < key)) { val = v2; key = k2; }
      }
      if (lane == 0) {
        int s   = (int)(key >> 16);
        int pos = (int)(key & 0xFFFFu);
        int rn  = (s == 255) ? (NB + blockIdx.x + (g << 8)) : (2 * NB + s - 1);
        float nx = posS[2 * rn], ny = posS[2 * rn + 1];
        float dx = nx - px, dy = ny - py;
        float d = sqrtf(dx * dx + dy * dy + 1e-12f);
        if (d > md) md = d;
        px = nx; py = ny;
        curS[g] = rn;
        if (s != 255) { actS[g][pos] = actS[g][cnt - 1]; cntS[g] = cnt - 1; }
      }
    }
    __syncthreads();  // B6
  }

  if (t == 0)   maxd_out[blockIdx.x] = md;
  if (t == 256) maxd_out[blockIdx.x + NBLK] = md;
}

__global__ __launch_bounds__(512) void reduce_k(const float* __restrict__ maxd,
                                               float* __restrict__ out)
{
  __shared__ float s[512];
  int t = threadIdx.x;
  s[t] = maxd[t];
  __syncthreads();
  for (int off = 256; off > 0; off >>= 1) {
    if (t < off) s[t] += s[t + off];
    __syncthreads();
  }
  if (t == 0) out[0] = s[0] * (1.0f / 512.0f);
}

extern "C" void kernel_launch(void* const* d_in, const int* in_sizes, int n_in,
                              void* d_out, int out_size, void* d_ws, size_t ws_size,
                              hipStream_t stream) {
  const float* outputs = (const float*)d_in[0];
  const float* Wemb    = (const float*)d_in[1];
  const float* bemb    = (const float*)d_in[2];
  const float* Wi      = (const float*)d_in[3];
  const float* Wh      = (const float*)d_in[4];
  const float* lb      = (const float*)d_in[5];
  const float* W1      = (const float*)d_in[6];
  const float* W2      = (const float*)d_in[7];
  const float* av      = (const float*)d_in[8];
  // d_in[9] = N (known constant 512)

  float* ws   = (float*)d_ws;
  float* EWi  = ws;                           // 1278 * 512
  float* W1eT = EWi  + (size_t)RTOT * 512;    // 128 * 1278
  float* maxd = W1eT + (size_t)HH * RTOT;     // 512

  hipLaunchKernelGGL(precompute_k, dim3(RTOT), dim3(HH), 0, stream,
                     outputs, Wemb, bemb, Wi, W1, lb, EWi, W1eT);
  hipLaunchKernelGGL(decode_k, dim3(NBLK), dim3(1024), 0, stream,
                     outputs, Wh, W2, av, EWi, W1eT, maxd);
  hipLaunchKernelGGL(reduce_k, dim3(1), dim3(512), 0, stream, maxd, (float*)d_out);
}

// Round 5
// 3587.590 us; speedup vs baseline: 4.2362x; 1.0297x over previous
//
#include <hip/hip_runtime.h>
#include <math.h>

// Problem constants (fixed by reference file)
#define NB   512    // N = batch of user pairs
#define MM   254    // M uav nodes
#define SS   256    // S = M + 2 graph nodes per b
#define HH   128    // H hidden
#define RTOT 1278   // 2N + M rows in `outputs`
#define NBLK 256    // decode blocks; each handles b and b+256

__device__ __forceinline__ float sigm(float x)   { return 1.0f / (1.0f + __expf(-x)); }
__device__ __forceinline__ float tanh_f(float x) { return 1.0f - 2.0f / (1.0f + __expf(2.0f * x)); }

// Per node row r: e = pos @ W_embed + b_embed (128),
//   EWiP[r][j] = float4(i,f,g,o) columns of e@lstm_Wi + lstm_b  (bias folded)
//   W1eP[h2][r] = float2(W1e[2h2], W1e[2h2+1])   (lane-coalesced over r)
__global__ __launch_bounds__(128) void precompute_k(
    const float* __restrict__ outputs, const float* __restrict__ Wemb,
    const float* __restrict__ bemb, const float* __restrict__ Wi,
    const float* __restrict__ W1, const float* __restrict__ lb,
    float4* __restrict__ EWiP, float2* __restrict__ W1eP)
{
  int r = blockIdx.x;
  int t = threadIdx.x;  // 128
  __shared__ float e[HH];
  __shared__ float w1e[HH];
  float px = outputs[2 * r], py = outputs[2 * r + 1];
  e[t] = px * Wemb[t] + py * Wemb[HH + t] + bemb[t];
  __syncthreads();
  float acc = 0.f;
#pragma unroll 8
  for (int h = 0; h < HH; ++h) acc = fmaf(e[h], W1[h * HH + t], acc);
  w1e[t] = acc;
  float g4[4];
#pragma unroll
  for (int c = 0; c < 4; ++c) {
    int j = t + c * HH;
    float a = 0.f;
#pragma unroll 8
    for (int h = 0; h < HH; ++h) a = fmaf(e[h], Wi[h * 512 + j], a);
    g4[c] = a + lb[j];
  }
  float4 v4; v4.x = g4[0]; v4.y = g4[1]; v4.z = g4[2]; v4.w = g4[3];
  EWiP[(size_t)r * HH + t] = v4;
  __syncthreads();
  if (t < 64) {
    float2 p; p.x = w1e[2 * t]; p.y = w1e[2 * t + 1];
    W1eP[(size_t)t * RTOT + r] = p;
  }
}

// One block per TWO batch elements (b, b+256). 1024 threads = 16 waves.
// Wh lives in registers (64/thread), W2 in registers (16/thread):
// gates & q phases have ZERO global loads (LDS broadcast + FMA only).
__global__ __launch_bounds__(1024) void decode_k(
    const float* __restrict__ outputs, const float* __restrict__ Wh,
    const float* __restrict__ W2, const float* __restrict__ av,
    const float4* __restrict__ EWiP, const float2* __restrict__ W1eP,
    float* __restrict__ maxd_out)
{
  const int t = threadIdx.x;   // 0..1023
  const int bid = blockIdx.x;

  __shared__ float posS[2 * RTOT];          // 10.2 KB
  __shared__ __align__(16) float hS[2][HH];
  __shared__ float qS[2][HH], vS[HH];
  __shared__ float pS[2][2][512];           // gates partials [g][khalf][j]
  __shared__ float qp[2][8][HH];            // q partials [g][kslice][j]
  __shared__ float lp[2][4][SS];            // logit partials [g][hquarter][u]
  __shared__ int   lsS[2][SS];              // node id s per slot u
  __shared__ int   actS[2][254];
  __shared__ int   cntS[2], curS[2];

  const int gj  = t & 511;       // gates column
  const int gh  = t >> 9;        // gates k-half
  const int qj  = t & 127;       // q column
  const int qq8 = t >> 7;        // q k-slice (0..7)
  const int lg  = t >> 9;        // logits batch slot
  const int lhq = (t >> 7) & 3;  // logits h-quarter
  const int lu  = t & 127;       // logits base node slot

  // ---- persistent register-resident weights (loaded once) ----
  float wreg[64];
#pragma unroll
  for (int i = 0; i < 64; ++i) wreg[i] = Wh[(size_t)(gh * 64 + i) * 512 + gj];
  float w2reg[16];
#pragma unroll
  for (int i = 0; i < 16; ++i) w2reg[i] = W2[(size_t)(qq8 * 16 + i) * HH + qj];

  for (int i = t; i < 2 * RTOT; i += 1024) posS[i] = outputs[i];
  if (t < 256) { int g = t >> 7, j = t & 127; hS[g][j] = 0.f; }
  if (t < HH) vS[t] = av[t];
  if (t < 254) actS[0][t] = t + 1;
  else if (t >= 512 && t < 766) actS[1][t - 512] = t - 511;
  if (t == 0)   { cntS[0] = 254; curS[0] = bid; }
  if (t == 512) { cntS[1] = 254; curS[1] = bid + NBLK; }
  __syncthreads();

  float px = 0.f, py = 0.f, md = 0.f;   // live in t==0 (g0) and t==512 (g1)
  if (t == 0)   { px = posS[2 * bid];            py = posS[2 * bid + 1]; }
  if (t == 512) { px = posS[2 * (bid + NBLK)];   py = posS[2 * (bid + NBLK) + 1]; }

  float creg = 0.f;                     // LSTM c-state, owned by t<256

  for (int k = 0; k < SS; ++k) {
    // ---- Phase A: EWi prefetch (latency hides under gates) + gates partials
    float4 ew4 = make_float4(0.f, 0.f, 0.f, 0.f);
    if (t < 256) ew4 = EWiP[(size_t)curS[t >> 7] * HH + (t & 127)];
    {
      const float4* h40 = (const float4*)(&hS[0][gh * 64]);  // wave-uniform => broadcast
      const float4* h41 = (const float4*)(&hS[1][gh * 64]);
      float a00 = 0.f, a01 = 0.f, a10 = 0.f, a11 = 0.f;
#pragma unroll
      for (int i = 0; i < 16; ++i) {
        float4 h0 = h40[i], h1 = h41[i];
        a00 = fmaf(h0.x, wreg[4 * i],     a00);
        a01 = fmaf(h0.y, wreg[4 * i + 1], a01);
        a00 = fmaf(h0.z, wreg[4 * i + 2], a00);
        a01 = fmaf(h0.w, wreg[4 * i + 3], a01);
        a10 = fmaf(h1.x, wreg[4 * i],     a10);
        a11 = fmaf(h1.y, wreg[4 * i + 1], a11);
        a10 = fmaf(h1.z, wreg[4 * i + 2], a10);
        a11 = fmaf(h1.w, wreg[4 * i + 3], a11);
      }
      pS[0][gh][gj] = a00 + a01;
      pS[1][gh][gj] = a10 + a11;
    }
    __syncthreads();  // B1

    // ---- Phase B: LSTM cell (t<256; order i,f,g,o)
    if (t < 256) {
      int g = t >> 7, jj = t & 127;
      float ei = ew4.x + (pS[g][0][jj]       + pS[g][1][jj]);
      float ef = ew4.y + (pS[g][0][128 + jj] + pS[g][1][128 + jj]);
      float eg = ew4.z + (pS[g][0][256 + jj] + pS[g][1][256 + jj]);
      float eo = ew4.w + (pS[g][0][384 + jj] + pS[g][1][384 + jj]);
      float iv = sigm(ei), fv = sigm(ef), gv = tanh_f(eg), ov = sigm(eo);
      float cn = fv * creg + iv * gv;
      creg = cn;
      hS[g][jj] = ov * tanh_f(cn);
    }
    __syncthreads();  // B2

    // ---- Phase C: q partials (register W2, LDS broadcast h)
    {
      const float* h0 = &hS[0][qq8 * 16];   // wave-uniform => broadcast
      const float* h1 = &hS[1][qq8 * 16];
      float p0 = 0.f, p1 = 0.f;
#pragma unroll
      for (int i = 0; i < 16; ++i) {
        float w = w2reg[i];
        p0 = fmaf(h0[i], w, p0);
        p1 = fmaf(h1[i], w, p1);
      }
      qp[0][qq8][qj] = p0;
      qp[1][qq8][qj] = p1;
    }
    __syncthreads();  // B3

    // ---- Phase D: q reduce (t<256)
    if (t < 256) {
      int g = t >> 7, jj = t & 127;
      qS[g][jj] = ((qp[g][0][jj] + qp[g][1][jj]) + (qp[g][2][jj] + qp[g][3][jj]))
                + ((qp[g][4][jj] + qp[g][5][jj]) + (qp[g][6][jj] + qp[g][7][jj]));
    }
    __syncthreads();  // B4

    // ---- Phase E: logits, 4-way h-split, 2 nodes/thread (independent chains)
    {
      int cnt = cntS[lg];
      int cntEff = cnt + (k > 0 ? 1 : 0);   // dst node re-enters for k>0
      int u0 = lu, u1 = lu + 128;
      bool e0 = u0 < cntEff, e1 = u1 < cntEff;
      int s0 = 0, s1 = 0;
      const float2 *wp0 = W1eP, *wp1 = W1eP;
      if (e0) {
        s0 = (u0 == cnt) ? 255 : actS[lg][u0];
        int r0 = (s0 == 255) ? (NB + bid + (lg << 8)) : (2 * NB + s0 - 1);
        wp0 = W1eP + (size_t)(lhq * 16) * RTOT + r0;
      }
      if (e1) {
        s1 = (u1 == cnt) ? 255 : actS[lg][u1];
        int r1 = (s1 == 255) ? (NB + bid + (lg << 8)) : (2 * NB + s1 - 1);
        wp1 = W1eP + (size_t)(lhq * 16) * RTOT + r1;
      }
      const float* qv = &qS[lg][lhq * 32];  // wave-uniform => broadcast
      const float* vv = &vS[lhq * 32];
      float a0x = 0.f, a0y = 0.f, a1x = 0.f, a1y = 0.f;
#pragma unroll 4
      for (int i = 0; i < 16; ++i) {
        float qa = qv[2 * i], qb = qv[2 * i + 1];
        float va = vv[2 * i], vb = vv[2 * i + 1];
        if (e0) {
          float2 w = wp0[(size_t)i * RTOT];
          a0x = fmaf(va, tanh_f(w.x + qa), a0x);
          a0y = fmaf(vb, tanh_f(w.y + qb), a0y);
        }
        if (e1) {
          float2 w = wp1[(size_t)i * RTOT];
          a1x = fmaf(va, tanh_f(w.x + qa), a1x);
          a1y = fmaf(vb, tanh_f(w.y + qb), a1y);
        }
      }
      if (e0) { lp[lg][lhq][u0] = a0x + a0y; if (lhq == 0) lsS[lg][u0] = s0; }
      if (e1) { lp[lg][lhq][u1] = a1x + a1y; if (lhq == 0) lsS[lg][u1] = s1; }
    }
    __syncthreads();  // B5

    // ---- Phase F: argmax + state update (wave 0 -> g0, wave 8 -> g1)
    if ((t < 64) || (t >= 512 && t < 576)) {
      int g = t >> 9;
      int lane = t & 63;
      int cnt = cntS[g];
      int cntEff = cnt + (k > 0 ? 1 : 0);
      float val = -INFINITY;
      unsigned key = 0xFFFFFFFFu;
#pragma unroll
      for (int c = 0; c < 4; ++c) {
        int u = lane + 64 * c;
        if (u < cntEff) {
          float v2 = (lp[g][0][u] + lp[g][1][u]) + (lp[g][2][u] + lp[g][3][u]);
          unsigned k2 = ((unsigned)lsS[g][u] << 16) | (unsigned)u;
          if (v2 > val || (v2 == val && k2 < key)) { val = v2; key = k2; }
        }
      }
#pragma unroll
      for (int off = 1; off < 64; off <<= 1) {
        float v2 = __shfl_xor(val, off);
        unsigned k2 = __shfl_xor(key, off);
        if (v2 > val || (v2 == val && k2 < key)) { val = v2; key = k2; }
      }
      if (lane == 0) {
        int s   = (int)(key >> 16);
        int pos = (int)(key & 0xFFFFu);
        int rn  = (s == 255) ? (NB + bid + (g << 8)) : (2 * NB + s - 1);
        float nx = posS[2 * rn], ny = posS[2 * rn + 1];
        float dx = nx - px, dy = ny - py;
        float d = sqrtf(dx * dx + dy * dy + 1e-12f);
        if (d > md) md = d;
        px = nx; py = ny;
        curS[g] = rn;
        if (s != 255) { actS[g][pos] = actS[g][cnt - 1]; cntS[g] = cnt - 1; }
      }
    }
    __syncthreads();  // B6
  }

  if (t == 0)   maxd_out[bid] = md;
  if (t == 512) maxd_out[bid + NBLK] = md;
}

__global__ __launch_bounds__(512) void reduce_k(const float* __restrict__ maxd,
                                               float* __restrict__ out)
{
  __shared__ float s[512];
  int t = threadIdx.x;
  s[t] = maxd[t];
  __syncthreads();
  for (int off = 256; off > 0; off >>= 1) {
    if (t < off) s[t] += s[t + off];
    __syncthreads();
  }
  if (t == 0) out[0] = s[0] * (1.0f / 512.0f);
}

extern "C" void kernel_launch(void* const* d_in, const int* in_sizes, int n_in,
                              void* d_out, int out_size, void* d_ws, size_t ws_size,
                              hipStream_t stream) {
  const float* outputs = (const float*)d_in[0];
  const float* Wemb    = (const float*)d_in[1];
  const float* bemb    = (const float*)d_in[2];
  const float* Wi      = (const float*)d_in[3];
  const float* Wh      = (const float*)d_in[4];
  const float* lb      = (const float*)d_in[5];
  const float* W1      = (const float*)d_in[6];
  const float* W2      = (const float*)d_in[7];
  const float* av      = (const float*)d_in[8];
  // d_in[9] = N (known constant 512)

  float* ws    = (float*)d_ws;
  float4* EWiP = (float4*)ws;                             // 1278*128 float4
  float2* W1eP = (float2*)(ws + (size_t)RTOT * 512);      // 64*1278 float2
  float*  maxd = ws + (size_t)RTOT * 512 + (size_t)HH * RTOT;  // 512

  hipLaunchKernelGGL(precompute_k, dim3(RTOT), dim3(HH), 0, stream,
                     outputs, Wemb, bemb, Wi, W1, lb, EWiP, W1eP);
  hipLaunchKernelGGL(decode_k, dim3(NBLK), dim3(1024), 0, stream,
                     outputs, Wh, W2, av, EWiP, W1eP, maxd);
  hipLaunchKernelGGL(reduce_k, dim3(1), dim3(512), 0, stream, maxd, (float*)d_out);
}

// Round 6
// 3580.225 us; speedup vs baseline: 4.2449x; 1.0021x over previous
//
#include <hip/hip_runtime.h>
#include <math.h>

// Problem constants (fixed by reference file)
#define NB   512    // N = batch of user pairs
#define MM   254    // M uav nodes
#define SS   256    // S = M + 2 graph nodes per b
#define HH   128    // H hidden
#define RTOT 1278   // 2N + M rows in `outputs`
#define NBLK 256    // decode blocks; each handles b and b+256

__device__ __forceinline__ float sigm(float x)   { return 1.0f / (1.0f + __expf(-x)); }
__device__ __forceinline__ float tanh_f(float x) { return 1.0f - 2.0f / (1.0f + __expf(2.0f * x)); }

// Per node row r: e = pos @ W_embed + b_embed (128),
//   EWiP[r][j] = float4(i,f,g,o) columns of e@lstm_Wi + lstm_b  (bias folded)
//   W1eP[h2][r] = float2(W1e[2h2], W1e[2h2+1])   (lane-coalesced over r)
__global__ __launch_bounds__(128) void precompute_k(
    const float* __restrict__ outputs, const float* __restrict__ Wemb,
    const float* __restrict__ bemb, const float* __restrict__ Wi,
    const float* __restrict__ W1, const float* __restrict__ lb,
    float4* __restrict__ EWiP, float2* __restrict__ W1eP)
{
  int r = blockIdx.x;
  int t = threadIdx.x;  // 128
  __shared__ float e[HH];
  __shared__ float w1e[HH];
  float px = outputs[2 * r], py = outputs[2 * r + 1];
  e[t] = px * Wemb[t] + py * Wemb[HH + t] + bemb[t];
  __syncthreads();
  float acc = 0.f;
#pragma unroll 8
  for (int h = 0; h < HH; ++h) acc = fmaf(e[h], W1[h * HH + t], acc);
  w1e[t] = acc;
  float g4[4];
#pragma unroll
  for (int c = 0; c < 4; ++c) {
    int j = t + c * HH;
    float a = 0.f;
#pragma unroll 8
    for (int h = 0; h < HH; ++h) a = fmaf(e[h], Wi[h * 512 + j], a);
    g4[c] = a + lb[j];
  }
  float4 v4; v4.x = g4[0]; v4.y = g4[1]; v4.z = g4[2]; v4.w = g4[3];
  EWiP[(size_t)r * HH + t] = v4;
  __syncthreads();
  if (t < 64) {
    float2 p; p.x = w1e[2 * t]; p.y = w1e[2 * t + 1];
    W1eP[(size_t)t * RTOT + r] = p;
  }
}

// One block per TWO batch elements (b, b+256). 1024 threads = 16 waves.
// __launch_bounds__(1024, 4): min 4 waves/EU = 16 waves/CU = THIS block only
// -> VGPR cap 128, so wreg[64]+w2reg[16] are genuinely register-resident.
__global__ __launch_bounds__(1024, 4) void decode_k(
    const float* __restrict__ outputs, const float* __restrict__ Wh,
    const float* __restrict__ W2, const float* __restrict__ av,
    const float4* __restrict__ EWiP, const float2* __restrict__ W1eP,
    float* __restrict__ maxd_out)
{
  const int t = threadIdx.x;   // 0..1023
  const int bid = blockIdx.x;

  __shared__ float posS[2 * RTOT];          // 10.2 KB
  __shared__ __align__(16) float hS[2][HH];
  __shared__ float qS[2][HH], vS[HH];
  __shared__ float pS[2][2][512];           // gates partials [g][khalf][j]
  __shared__ float qp[2][8][HH];            // q partials [g][kslice][j]
  __shared__ float lp[2][4][SS];            // logit partials [g][hquarter][u]
  __shared__ int   lsS[2][SS];              // node id s per slot u
  __shared__ int   actS[2][254];
  __shared__ int   cntS[2], curS[2];

  const int gj  = t & 511;       // gates column
  const int gh  = t >> 9;        // gates k-half
  const int qj  = t & 127;       // q column
  const int qq8 = t >> 7;        // q k-slice (0..7)
  const int lg  = t >> 9;        // logits batch slot
  const int lhq = (t >> 7) & 3;  // logits h-quarter
  const int lu  = t & 127;       // logits base node slot

  // ---- persistent register-resident weights (loaded once) ----
  float wreg[64];
#pragma unroll
  for (int i = 0; i < 64; ++i) wreg[i] = Wh[(size_t)(gh * 64 + i) * 512 + gj];
  float w2reg[16];
#pragma unroll
  for (int i = 0; i < 16; ++i) w2reg[i] = W2[(size_t)(qq8 * 16 + i) * HH + qj];

  for (int i = t; i < 2 * RTOT; i += 1024) posS[i] = outputs[i];
  if (t < 256) { int g = t >> 7, j = t & 127; hS[g][j] = 0.f; }
  if (t < HH) vS[t] = av[t];
  if (t < 254) actS[0][t] = t + 1;
  else if (t >= 512 && t < 766) actS[1][t - 512] = t - 511;
  if (t == 0)   { cntS[0] = 254; curS[0] = bid; }
  if (t == 512) { cntS[1] = 254; curS[1] = bid + NBLK; }
  __syncthreads();

  float px = 0.f, py = 0.f, md = 0.f;   // live in t==0 (g0) and t==512 (g1)
  if (t == 0)   { px = posS[2 * bid];            py = posS[2 * bid + 1]; }
  if (t == 512) { px = posS[2 * (bid + NBLK)];   py = posS[2 * (bid + NBLK) + 1]; }

  float creg = 0.f;                     // LSTM c-state, owned by t<256

  for (int k = 0; k < SS; ++k) {
    // ---- Phase A: EWi prefetch (latency hides under gates) + gates partials
    float4 ew4 = make_float4(0.f, 0.f, 0.f, 0.f);
    if (t < 256) ew4 = EWiP[(size_t)curS[t >> 7] * HH + (t & 127)];
    {
      const float4* h40 = (const float4*)(&hS[0][gh * 64]);  // wave-uniform => broadcast
      const float4* h41 = (const float4*)(&hS[1][gh * 64]);
      float a00 = 0.f, a01 = 0.f, a10 = 0.f, a11 = 0.f;
#pragma unroll
      for (int i = 0; i < 16; ++i) {
        float4 h0 = h40[i], h1 = h41[i];
        a00 = fmaf(h0.x, wreg[4 * i],     a00);
        a01 = fmaf(h0.y, wreg[4 * i + 1], a01);
        a00 = fmaf(h0.z, wreg[4 * i + 2], a00);
        a01 = fmaf(h0.w, wreg[4 * i + 3], a01);
        a10 = fmaf(h1.x, wreg[4 * i],     a10);
        a11 = fmaf(h1.y, wreg[4 * i + 1], a11);
        a10 = fmaf(h1.z, wreg[4 * i + 2], a10);
        a11 = fmaf(h1.w, wreg[4 * i + 3], a11);
      }
      pS[0][gh][gj] = a00 + a01;
      pS[1][gh][gj] = a10 + a11;
    }
    __syncthreads();  // B1

    // ---- Phase B: LSTM cell (t<256; order i,f,g,o)
    if (t < 256) {
      int g = t >> 7, jj = t & 127;
      float ei = ew4.x + (pS[g][0][jj]       + pS[g][1][jj]);
      float ef = ew4.y + (pS[g][0][128 + jj] + pS[g][1][128 + jj]);
      float eg = ew4.z + (pS[g][0][256 + jj] + pS[g][1][256 + jj]);
      float eo = ew4.w + (pS[g][0][384 + jj] + pS[g][1][384 + jj]);
      float iv = sigm(ei), fv = sigm(ef), gv = tanh_f(eg), ov = sigm(eo);
      float cn = fv * creg + iv * gv;
      creg = cn;
      hS[g][jj] = ov * tanh_f(cn);
    }
    __syncthreads();  // B2

    // ---- Phase C: q partials (register W2, LDS broadcast h)
    {
      const float* h0 = &hS[0][qq8 * 16];   // wave-uniform => broadcast
      const float* h1 = &hS[1][qq8 * 16];
      float p0 = 0.f, p1 = 0.f;
#pragma unroll
      for (int i = 0; i < 16; ++i) {
        float w = w2reg[i];
        p0 = fmaf(h0[i], w, p0);
        p1 = fmaf(h1[i], w, p1);
      }
      qp[0][qq8][qj] = p0;
      qp[1][qq8][qj] = p1;
    }
    __syncthreads();  // B3

    // ---- Phase D: q reduce (t<256)
    if (t < 256) {
      int g = t >> 7, jj = t & 127;
      qS[g][jj] = ((qp[g][0][jj] + qp[g][1][jj]) + (qp[g][2][jj] + qp[g][3][jj]))
                + ((qp[g][4][jj] + qp[g][5][jj]) + (qp[g][6][jj] + qp[g][7][jj]));
    }
    __syncthreads();  // B4

    // ---- Phase E: logits, 4-way h-split, 2 nodes/thread (independent chains)
    {
      int cnt = cntS[lg];
      int cntEff = cnt + (k > 0 ? 1 : 0);   // dst node re-enters for k>0
      int u0 = lu, u1 = lu + 128;
      bool e0 = u0 < cntEff, e1 = u1 < cntEff;
      int s0 = 0, s1 = 0;
      const float2 *wp0 = W1eP, *wp1 = W1eP;
      if (e0) {
        s0 = (u0 == cnt) ? 255 : actS[lg][u0];
        int r0 = (s0 == 255) ? (NB + bid + (lg << 8)) : (2 * NB + s0 - 1);
        wp0 = W1eP + (size_t)(lhq * 16) * RTOT + r0;
      }
      if (e1) {
        s1 = (u1 == cnt) ? 255 : actS[lg][u1];
        int r1 = (s1 == 255) ? (NB + bid + (lg << 8)) : (2 * NB + s1 - 1);
        wp1 = W1eP + (size_t)(lhq * 16) * RTOT + r1;
      }
      const float* qv = &qS[lg][lhq * 32];  // wave-uniform => broadcast
      const float* vv = &vS[lhq * 32];
      float a0x = 0.f, a0y = 0.f, a1x = 0.f, a1y = 0.f;
#pragma unroll 4
      for (int i = 0; i < 16; ++i) {
        float qa = qv[2 * i], qb = qv[2 * i + 1];
        float va = vv[2 * i], vb = vv[2 * i + 1];
        if (e0) {
          float2 w = wp0[(size_t)i * RTOT];
          a0x = fmaf(va, tanh_f(w.x + qa), a0x);
          a0y = fmaf(vb, tanh_f(w.y + qb), a0y);
        }
        if (e1) {
          float2 w = wp1[(size_t)i * RTOT];
          a1x = fmaf(va, tanh_f(w.x + qa), a1x);
          a1y = fmaf(vb, tanh_f(w.y + qb), a1y);
        }
      }
      if (e0) { lp[lg][lhq][u0] = a0x + a0y; if (lhq == 0) lsS[lg][u0] = s0; }
      if (e1) { lp[lg][lhq][u1] = a1x + a1y; if (lhq == 0) lsS[lg][u1] = s1; }
    }
    __syncthreads();  // B5

    // ---- Phase F: argmax + state update (wave 0 -> g0, wave 8 -> g1)
    if ((t < 64) || (t >= 512 && t < 576)) {
      int g = t >> 9;
      int lane = t & 63;
      int cnt = cntS[g];
      int cntEff = cnt + (k > 0 ? 1 : 0);
      float val = -INFINITY;
      unsigned key = 0xFFFFFFFFu;
#pragma unroll
      for (int c = 0; c < 4; ++c) {
        int u = lane + 64 * c;
        if (u < cntEff) {
          float v2 = (lp[g][0][u] + lp[g][1][u]) + (lp[g][2][u] + lp[g][3][u]);
          unsigned k2 = ((unsigned)lsS[g][u] << 16) | (unsigned)u;
          if (v2 > val || (v2 == val && k2 < key)) { val = v2; key = k2; }
        }
      }
#pragma unroll
      for (int off = 1; off < 64; off <<= 1) {
        float v2 = __shfl_xor(val, off);
        unsigned k2 = __shfl_xor(key, off);
        if (v2 > val || (v2 == val && k2 < key)) { val = v2; key = k2; }
      }
      if (lane == 0) {
        int s   = (int)(key >> 16);
        int pos = (int)(key & 0xFFFFu);
        int rn  = (s == 255) ? (NB + bid + (g << 8)) : (2 * NB + s - 1);
        float nx = posS[2 * rn], ny = posS[2 * rn + 1];
        float dx = nx - px, dy = ny - py;
        float d = sqrtf(dx * dx + dy * dy + 1e-12f);
        if (d > md) md = d;
        px = nx; py = ny;
        curS[g] = rn;
        if (s != 255) { actS[g][pos] = actS[g][cnt - 1]; cntS[g] = cnt - 1; }
      }
    }
    __syncthreads();  // B6
  }

  if (t == 0)   maxd_out[bid] = md;
  if (t == 512) maxd_out[bid + NBLK] = md;
}

__global__ __launch_bounds__(512) void reduce_k(const float* __restrict__ maxd,
                                               float* __restrict__ out)
{
  __shared__ float s[512];
  int t = threadIdx.x;
  s[t] = maxd[t];
  __syncthreads();
  for (int off = 256; off > 0; off >>= 1) {
    if (t < off) s[t] += s[t + off];
    __syncthreads();
  }
  if (t == 0) out[0] = s[0] * (1.0f / 512.0f);
}

extern "C" void kernel_launch(void* const* d_in, const int* in_sizes, int n_in,
                              void* d_out, int out_size, void* d_ws, size_t ws_size,
                              hipStream_t stream) {
  const float* outputs = (const float*)d_in[0];
  const float* Wemb    = (const float*)d_in[1];
  const float* bemb    = (const float*)d_in[2];
  const float* Wi      = (const float*)d_in[3];
  const float* Wh      = (const float*)d_in[4];
  const float* lb      = (const float*)d_in[5];
  const float* W1      = (const float*)d_in[6];
  const float* W2      = (const float*)d_in[7];
  const float* av      = (const float*)d_in[8];
  // d_in[9] = N (known constant 512)

  float* ws    = (float*)d_ws;
  float4* EWiP = (float4*)ws;                             // 1278*128 float4
  float2* W1eP = (float2*)(ws + (size_t)RTOT * 512);      // 64*1278 float2
  float*  maxd = ws + (size_t)RTOT * 512 + (size_t)HH * RTOT;  // 512

  hipLaunchKernelGGL(precompute_k, dim3(RTOT), dim3(HH), 0, stream,
                     outputs, Wemb, bemb, Wi, W1, lb, EWiP, W1eP);
  hipLaunchKernelGGL(decode_k, dim3(NBLK), dim3(1024), 0, stream,
                     outputs, Wh, W2, av, EWiP, W1eP, maxd);
  hipLaunchKernelGGL(reduce_k, dim3(1), dim3(512), 0, stream, maxd, (float*)d_out);
}

// Round 7
// 3560.632 us; speedup vs baseline: 4.2683x; 1.0055x over previous
//
#include <hip/hip_runtime.h>
#include <math.h>

// Problem constants (fixed by reference file)
#define NB   512    // N = batch of user pairs
#define MM   254    // M uav nodes
#define SS   256    // S = M + 2 graph nodes per b
#define HH   128    // H hidden
#define RTOT 1278   // 2N + M rows in `outputs`
#define NBLK 256    // decode blocks; each handles b and b+256

__device__ __forceinline__ float sigm(float x)   { return 1.0f / (1.0f + __expf(-x)); }
__device__ __forceinline__ float tanh_f(float x) { return 1.0f - 2.0f / (1.0f + __expf(2.0f * x)); }

// Per node row r: e = pos @ W_embed + b_embed (128),
//   EWiP[r][j] = float4(i,f,g,o) columns of e@lstm_Wi + lstm_b  (bias folded)
//   W1eP[h2][r] = float2(W1e[2h2], W1e[2h2+1])   (lane-coalesced over r)
__global__ __launch_bounds__(128) void precompute_k(
    const float* __restrict__ outputs, const float* __restrict__ Wemb,
    const float* __restrict__ bemb, const float* __restrict__ Wi,
    const float* __restrict__ W1, const float* __restrict__ lb,
    float4* __restrict__ EWiP, float2* __restrict__ W1eP)
{
  int r = blockIdx.x;
  int t = threadIdx.x;  // 128
  __shared__ float e[HH];
  __shared__ float w1e[HH];
  float px = outputs[2 * r], py = outputs[2 * r + 1];
  e[t] = px * Wemb[t] + py * Wemb[HH + t] + bemb[t];
  __syncthreads();
  float acc = 0.f;
#pragma unroll 8
  for (int h = 0; h < HH; ++h) acc = fmaf(e[h], W1[h * HH + t], acc);
  w1e[t] = acc;
  float g4[4];
#pragma unroll
  for (int c = 0; c < 4; ++c) {
    int j = t + c * HH;
    float a = 0.f;
#pragma unroll 8
    for (int h = 0; h < HH; ++h) a = fmaf(e[h], Wi[h * 512 + j], a);
    g4[c] = a + lb[j];
  }
  float4 v4; v4.x = g4[0]; v4.y = g4[1]; v4.z = g4[2]; v4.w = g4[3];
  EWiP[(size_t)r * HH + t] = v4;
  __syncthreads();
  if (t < 64) {
    float2 p; p.x = w1e[2 * t]; p.y = w1e[2 * t + 1];
    W1eP[(size_t)t * RTOT + r] = p;
  }
}

// One block per TWO batch elements (b, b+256). 1024 threads = 16 waves.
// amdgpu_waves_per_eu(4,4): pin EXACTLY 4 waves/EU (16 waves/CU = 1 block/CU,
// which is all the 256-block grid can use anyway) -> VGPR budget 128, so
// wreg[64]+w2reg[16] are genuinely register-resident with no spill.
__global__ __attribute__((amdgpu_waves_per_eu(4, 4)))
__launch_bounds__(1024) void decode_k(
    const float* __restrict__ outputs, const float* __restrict__ Wh,
    const float* __restrict__ W2, const float* __restrict__ av,
    const float4* __restrict__ EWiP, const float2* __restrict__ W1eP,
    float* __restrict__ maxd_out)
{
  const int t = threadIdx.x;   // 0..1023
  const int bid = blockIdx.x;

  __shared__ float posS[2 * RTOT];          // 10.2 KB
  __shared__ __align__(16) float hS[2][HH];
  __shared__ float qS[2][HH], vS[HH];
  __shared__ float pS[2][2][512];           // gates partials [g][khalf][j]
  __shared__ float qp[2][8][HH];            // q partials [g][kslice][j]
  __shared__ float lp[2][4][SS];            // logit partials [g][hquarter][u]
  __shared__ int   lsS[2][SS];              // node id s per slot u
  __shared__ int   actS[2][254];
  __shared__ int   cntS[2], curS[2];

  const int gj  = t & 511;       // gates column
  const int gh  = t >> 9;        // gates k-half
  const int qj  = t & 127;       // q column
  const int qq8 = t >> 7;        // q k-slice (0..7)
  const int lg  = t >> 9;        // logits batch slot
  const int lhq = (t >> 7) & 3;  // logits h-quarter
  const int lu  = t & 127;       // logits base node slot

  // ---- persistent register-resident weights (loaded once) ----
  float wreg[64];
#pragma unroll
  for (int i = 0; i < 64; ++i) wreg[i] = Wh[(size_t)(gh * 64 + i) * 512 + gj];
  float w2reg[16];
#pragma unroll
  for (int i = 0; i < 16; ++i) w2reg[i] = W2[(size_t)(qq8 * 16 + i) * HH + qj];

  for (int i = t; i < 2 * RTOT; i += 1024) posS[i] = outputs[i];
  if (t < 256) { int g = t >> 7, j = t & 127; hS[g][j] = 0.f; }
  if (t < HH) vS[t] = av[t];
  if (t < 254) actS[0][t] = t + 1;
  else if (t >= 512 && t < 766) actS[1][t - 512] = t - 511;
  if (t == 0)   { cntS[0] = 254; curS[0] = bid; }
  if (t == 512) { cntS[1] = 254; curS[1] = bid + NBLK; }
  __syncthreads();

  float px = 0.f, py = 0.f, md = 0.f;   // live in t==0 (g0) and t==512 (g1)
  if (t == 0)   { px = posS[2 * bid];            py = posS[2 * bid + 1]; }
  if (t == 512) { px = posS[2 * (bid + NBLK)];   py = posS[2 * (bid + NBLK) + 1]; }

  float creg = 0.f;                     // LSTM c-state, owned by t<256

  for (int k = 0; k < SS; ++k) {
    // ---- Phase A: EWi prefetch (latency hides under gates) + gates partials
    float4 ew4 = make_float4(0.f, 0.f, 0.f, 0.f);
    if (t < 256) ew4 = EWiP[(size_t)curS[t >> 7] * HH + (t & 127)];
    {
      const float4* h40 = (const float4*)(&hS[0][gh * 64]);  // wave-uniform => broadcast
      const float4* h41 = (const float4*)(&hS[1][gh * 64]);
      float a00 = 0.f, a01 = 0.f, a10 = 0.f, a11 = 0.f;
#pragma unroll
      for (int i = 0; i < 16; ++i) {
        float4 h0 = h40[i], h1 = h41[i];
        a00 = fmaf(h0.x, wreg[4 * i],     a00);
        a01 = fmaf(h0.y, wreg[4 * i + 1], a01);
        a00 = fmaf(h0.z, wreg[4 * i + 2], a00);
        a01 = fmaf(h0.w, wreg[4 * i + 3], a01);
        a10 = fmaf(h1.x, wreg[4 * i],     a10);
        a11 = fmaf(h1.y, wreg[4 * i + 1], a11);
        a10 = fmaf(h1.z, wreg[4 * i + 2], a10);
        a11 = fmaf(h1.w, wreg[4 * i + 3], a11);
      }
      pS[0][gh][gj] = a00 + a01;
      pS[1][gh][gj] = a10 + a11;
    }
    __syncthreads();  // B1

    // ---- Phase B: LSTM cell (t<256; order i,f,g,o)
    if (t < 256) {
      int g = t >> 7, jj = t & 127;
      float ei = ew4.x + (pS[g][0][jj]       + pS[g][1][jj]);
      float ef = ew4.y + (pS[g][0][128 + jj] + pS[g][1][128 + jj]);
      float eg = ew4.z + (pS[g][0][256 + jj] + pS[g][1][256 + jj]);
      float eo = ew4.w + (pS[g][0][384 + jj] + pS[g][1][384 + jj]);
      float iv = sigm(ei), fv = sigm(ef), gv = tanh_f(eg), ov = sigm(eo);
      float cn = fv * creg + iv * gv;
      creg = cn;
      hS[g][jj] = ov * tanh_f(cn);
    }
    __syncthreads();  // B2

    // ---- Phase C: q partials (register W2, LDS broadcast h)
    {
      const float* h0 = &hS[0][qq8 * 16];   // wave-uniform => broadcast
      const float* h1 = &hS[1][qq8 * 16];
      float p0 = 0.f, p1 = 0.f;
#pragma unroll
      for (int i = 0; i < 16; ++i) {
        float w = w2reg[i];
        p0 = fmaf(h0[i], w, p0);
        p1 = fmaf(h1[i], w, p1);
      }
      qp[0][qq8][qj] = p0;
      qp[1][qq8][qj] = p1;
    }
    __syncthreads();  // B3

    // ---- Phase D: q reduce (t<256)
    if (t < 256) {
      int g = t >> 7, jj = t & 127;
      qS[g][jj] = ((qp[g][0][jj] + qp[g][1][jj]) + (qp[g][2][jj] + qp[g][3][jj]))
                + ((qp[g][4][jj] + qp[g][5][jj]) + (qp[g][6][jj] + qp[g][7][jj]));
    }
    __syncthreads();  // B4

    // ---- Phase E: logits, 4-way h-split, 2 nodes/thread (independent chains)
    {
      int cnt = cntS[lg];
      int cntEff = cnt + (k > 0 ? 1 : 0);   // dst node re-enters for k>0
      int u0 = lu, u1 = lu + 128;
      bool e0 = u0 < cntEff, e1 = u1 < cntEff;
      int s0 = 0, s1 = 0;
      const float2 *wp0 = W1eP, *wp1 = W1eP;
      if (e0) {
        s0 = (u0 == cnt) ? 255 : actS[lg][u0];
        int r0 = (s0 == 255) ? (NB + bid + (lg << 8)) : (2 * NB + s0 - 1);
        wp0 = W1eP + (size_t)(lhq * 16) * RTOT + r0;
      }
      if (e1) {
        s1 = (u1 == cnt) ? 255 : actS[lg][u1];
        int r1 = (s1 == 255) ? (NB + bid + (lg << 8)) : (2 * NB + s1 - 1);
        wp1 = W1eP + (size_t)(lhq * 16) * RTOT + r1;
      }
      const float* qv = &qS[lg][lhq * 32];  // wave-uniform => broadcast
      const float* vv = &vS[lhq * 32];
      float a0x = 0.f, a0y = 0.f, a1x = 0.f, a1y = 0.f;
#pragma unroll 4
      for (int i = 0; i < 16; ++i) {
        float qa = qv[2 * i], qb = qv[2 * i + 1];
        float va = vv[2 * i], vb = vv[2 * i + 1];
        if (e0) {
          float2 w = wp0[(size_t)i * RTOT];
          a0x = fmaf(va, tanh_f(w.x + qa), a0x);
          a0y = fmaf(vb, tanh_f(w.y + qb), a0y);
        }
        if (e1) {
          float2 w = wp1[(size_t)i * RTOT];
          a1x = fmaf(va, tanh_f(w.x + qa), a1x);
          a1y = fmaf(vb, tanh_f(w.y + qb), a1y);
        }
      }
      if (e0) { lp[lg][lhq][u0] = a0x + a0y; if (lhq == 0) lsS[lg][u0] = s0; }
      if (e1) { lp[lg][lhq][u1] = a1x + a1y; if (lhq == 0) lsS[lg][u1] = s1; }
    }
    __syncthreads();  // B5

    // ---- Phase F: argmax + state update (wave 0 -> g0, wave 8 -> g1)
    if ((t < 64) || (t >= 512 && t < 576)) {
      int g = t >> 9;
      int lane = t & 63;
      int cnt = cntS[g];
      int cntEff = cnt + (k > 0 ? 1 : 0);
      float val = -INFINITY;
      unsigned key = 0xFFFFFFFFu;
#pragma unroll
      for (int c = 0; c < 4; ++c) {
        int u = lane + 64 * c;
        if (u < cntEff) {
          float v2 = (lp[g][0][u] + lp[g][1][u]) + (lp[g][2][u] + lp[g][3][u]);
          unsigned k2 = ((unsigned)lsS[g][u] << 16) | (unsigned)u;
          if (v2 > val || (v2 == val && k2 < key)) { val = v2; key = k2; }
        }
      }
#pragma unroll
      for (int off = 1; off < 64; off <<= 1) {
        float v2 = __shfl_xor(val, off);
        unsigned k2 = __shfl_xor(key, off);
        if (v2 > val || (v2 == val && k2 < key)) { val = v2; key = k2; }
      }
      if (lane == 0) {
        int s   = (int)(key >> 16);
        int pos = (int)(key & 0xFFFFu);
        int rn  = (s == 255) ? (NB + bid + (g << 8)) : (2 * NB + s - 1);
        float nx = posS[2 * rn], ny = posS[2 * rn + 1];
        float dx = nx - px, dy = ny - py;
        float d = sqrtf(dx * dx + dy * dy + 1e-12f);
        if (d > md) md = d;
        px = nx; py = ny;
        curS[g] = rn;
        if (s != 255) { actS[g][pos] = actS[g][cnt - 1]; cntS[g] = cnt - 1; }
      }
    }
    __syncthreads();  // B6
  }

  if (t == 0)   maxd_out[bid] = md;
  if (t == 512) maxd_out[bid + NBLK] = md;
}

__global__ __launch_bounds__(512) void reduce_k(const float* __restrict__ maxd,
                                               float* __restrict__ out)
{
  __shared__ float s[512];
  int t = threadIdx.x;
  s[t] = maxd[t];
  __syncthreads();
  for (int off = 256; off > 0; off >>= 1) {
    if (t < off) s[t] += s[t + off];
    __syncthreads();
  }
  if (t == 0) out[0] = s[0] * (1.0f / 512.0f);
}

extern "C" void kernel_launch(void* const* d_in, const int* in_sizes, int n_in,
                              void* d_out, int out_size, void* d_ws, size_t ws_size,
                              hipStream_t stream) {
  const float* outputs = (const float*)d_in[0];
  const float* Wemb    = (const float*)d_in[1];
  const float* bemb    = (const float*)d_in[2];
  const float* Wi      = (const float*)d_in[3];
  const float* Wh      = (const float*)d_in[4];
  const float* lb      = (const float*)d_in[5];
  const float* W1      = (const float*)d_in[6];
  const float* W2      = (const float*)d_in[7];
  const float* av      = (const float*)d_in[8];
  // d_in[9] = N (known constant 512)

  float* ws    = (float*)d_ws;
  float4* EWiP = (float4*)ws;                             // 1278*128 float4
  float2* W1eP = (float2*)(ws + (size_t)RTOT * 512);      // 64*1278 float2
  float*  maxd = ws + (size_t)RTOT * 512 + (size_t)HH * RTOT;  // 512

  hipLaunchKernelGGL(precompute_k, dim3(RTOT), dim3(HH), 0, stream,
                     outputs, Wemb, bemb, Wi, W1, lb, EWiP, W1eP);
  hipLaunchKernelGGL(decode_k, dim3(NBLK), dim3(1024), 0, stream,
                     outputs, Wh, W2, av, EWiP, W1eP, maxd);
  hipLaunchKernelGGL(reduce_k, dim3(1), dim3(512), 0, stream, maxd, (float*)d_out);
}